// Round 10
// baseline (256.835 us; speedup 1.0000x reference)
//
#include <hip/hip_runtime.h>

#define NROWS 8192
#define HALF  4096
#define DIM   256
#define JS    32                 // j-splits across grid
#define JRANGE 256               // columns per block
#define JTILES 16                // 16-row j-tiles per block
#define IPB   128                // i rows per block (4 waves x 32)
#define IPW   32                 // i rows per wave

typedef short bf16x8 __attribute__((ext_vector_type(8)));
typedef float f32x4  __attribute__((ext_vector_type(4)));

__device__ __forceinline__ unsigned short f2bf(float f) {
    unsigned int u = __float_as_uint(f);
    u += 0x7FFFu + ((u >> 16) & 1u);          // round-to-nearest-even
    return (unsigned short)(u >> 16);
}

// --- prep: zb = bf16(sqrt(2)*z) (MFMA then yields sim units directly),
//     exact fp32 positive dots, out = 0 ---
__global__ void k_prep(const float* __restrict__ z1, const float* __restrict__ z2,
                       unsigned short* __restrict__ zb, float* __restrict__ pos,
                       float* __restrict__ out) {
    if (blockIdx.x == 0 && threadIdx.x == 0) *out = 0.0f;
    const float R2 = 1.41421356237309515f;     // sqrt(2): (R2*z)·(R2*z) = 2*z·z = sim
    int w = threadIdx.x >> 6, lane = threadIdx.x & 63;
    int row = blockIdx.x * 4 + w;              // 0 .. 4095
    float4 a = *(const float4*)(z1 + (size_t)row * DIM + lane * 4);
    float4 b = *(const float4*)(z2 + (size_t)row * DIM + lane * 4);

    uint2 pa, pb;
    pa.x = (unsigned int)f2bf(a.x*R2) | ((unsigned int)f2bf(a.y*R2) << 16);
    pa.y = (unsigned int)f2bf(a.z*R2) | ((unsigned int)f2bf(a.w*R2) << 16);
    pb.x = (unsigned int)f2bf(b.x*R2) | ((unsigned int)f2bf(b.y*R2) << 16);
    pb.y = (unsigned int)f2bf(b.z*R2) | ((unsigned int)f2bf(b.w*R2) << 16);
    *(uint2*)(zb + (size_t)row * DIM + lane * 4)          = pa;
    *(uint2*)(zb + (size_t)(row + HALF) * DIM + lane * 4) = pb;

    float d = a.x * b.x + a.y * b.y + a.z * b.z + a.w * b.w;
    #pragma unroll
    for (int k = 32; k; k >>= 1) d += __shfl_xor(d, k);
    if (lane == 0) pos[row] = 2.0f * d;        // exact fp32, sim units
}

// ---------------- main: MFMA matmul + online LSE, NO LDS, NO BARRIERS ----------------
// Round-9 lesson: barrier-lockstep 2-phase staging caps MfmaUtil at 30% with no
// pipe saturated, and LDS reads cost 17K conflict-cycles/CU. zb (4MB) fits each
// XCD's L2 and tiles are L1-reusable, so stream af straight from global to regs
// (reg double-buffer, issued one tile ahead). Waves fully decoupled.
__global__ __launch_bounds__(256, 3)
void k_main(const unsigned short* __restrict__ zb, float2* __restrict__ part) {
    const int tid  = threadIdx.x;
    const int w    = tid >> 6;
    const int lane = tid & 63;
    const int col  = lane & 15;        // i-local / j-row within tile
    const int kg   = lane >> 4;        // k-group
    const int ib   = blockIdx.x & 63;  // 64 i-tiles of 128
    const int js   = blockIdx.x >> 6;  // 32 j-splits
    const int iw   = ib * IPB + w * IPW;
    const int jb0  = js * JRANGE;
    const int dr   = col - kg * 4;     // acc reg index hitting the diagonal
    const int dt   = (iw - jb0) >> 4;  // tile index of diagonal for subtile 0

    const char* zbb = (const char*)zb;

    // i-panel: 32 rows straight into registers (64 VGPRs)
    bf16x8 bf[2][8];
    {
        const char* bp = zbb + ((size_t)(iw + col) << 9) + kg * 16;
        #pragma unroll
        for (int kk = 0; kk < 8; ++kk) bf[0][kk] = *(const bf16x8*)(bp + kk * 64);
        #pragma unroll
        for (int kk = 0; kk < 8; ++kk) bf[1][kk] = *(const bf16x8*)(bp + 8192 + kk * 64);
    }

    float m0 = -1e30f, m1 = -1e30f, l0 = 0.0f, l1 = 0.0f;

    // j-tile base pointer for this lane: row (jb0+col), bytes kg*16 + kk*64
    const char* pa = zbb + ((size_t)(jb0 + col) << 9) + kg * 16;

#define LOADAF(AF, OFF) do { \
    _Pragma("unroll") \
    for (int kk = 0; kk < 8; ++kk) \
        AF[kk] = *(const bf16x8*)(pa + (OFF) + kk * 64); \
} while (0)

#define MASKD(X) do { \
    _Pragma("unroll") \
    for (int r = 0; r < 4; ++r) if (dr == r) X[r] = -1e30f; \
} while (0)

#define LSE0(X) do { \
    float t0 = fmaxf(fmaxf(X[0], X[1]), fmaxf(X[2], X[3])); \
    if (__any(t0 > m0)) { \
        float mn = fmaxf(m0, t0); \
        l0 *= __expf(m0 - mn); \
        m0 = mn; \
    } \
    l0 += __expf(X[0] - m0) + __expf(X[1] - m0) \
        + __expf(X[2] - m0) + __expf(X[3] - m0); \
} while (0)

#define LSE1(X) do { \
    float t0 = fmaxf(fmaxf(X[0], X[1]), fmaxf(X[2], X[3])); \
    if (__any(t0 > m1)) { \
        float mn = fmaxf(m1, t0); \
        l1 *= __expf(m1 - mn); \
        m1 = mn; \
    } \
    l1 += __expf(X[0] - m1) + __expf(X[1] - m1) \
        + __expf(X[2] - m1) + __expf(X[3] - m1); \
} while (0)

#define COMP(AF, T) do { \
    f32x4 a0 = {0.f, 0.f, 0.f, 0.f}; \
    f32x4 a1 = a0; \
    _Pragma("unroll") \
    for (int kk = 0; kk < 8; ++kk) { \
        a0 = __builtin_amdgcn_mfma_f32_16x16x32_bf16(AF[kk], bf[0][kk], a0, 0, 0, 0); \
        a1 = __builtin_amdgcn_mfma_f32_16x16x32_bf16(AF[kk], bf[1][kk], a1, 0, 0, 0); \
    } \
    const int dd = (T) - dt; \
    if (dd == 0) MASKD(a0); \
    if (dd == 1) MASKD(a1); \
    LSE0(a0); \
    LSE1(a1); \
} while (0)

    bf16x8 af0[8], af1[8];
    LOADAF(af0, 0);                        // tile 0
    #pragma unroll
    for (int u = 0; u < JTILES / 2 - 1; ++u) {
        LOADAF(af1, 8192);                 // tile 2u+1 (issued a tile ahead)
        COMP(af0, 2 * u);
        LOADAF(af0, 16384);                // tile 2u+2
        COMP(af1, 2 * u + 1);
        pa += 16384;
    }
    LOADAF(af1, 8192);                     // last tile
    COMP(af0, JTILES - 2);
    COMP(af1, JTILES - 1);

#undef LOADAF
#undef MASKD
#undef LSE0
#undef LSE1
#undef COMP

    // merge the 4 kg groups holding the same i (lanes col, col+16, col+32, col+48)
    {
        float mm = m0, ll = l0;
        #pragma unroll
        for (int msk = 16; msk <= 32; msk <<= 1) {
            float mo  = __shfl_xor(mm, msk);
            float lo_ = __shfl_xor(ll, msk);
            float mn  = fmaxf(mm, mo);
            ll = ll * __expf(mm - mn) + lo_ * __expf(mo - mn);
            mm = mn;
        }
        if (kg == 0) part[(size_t)(iw + col) * JS + js] = make_float2(mm, ll);
    }
    {
        float mm = m1, ll = l1;
        #pragma unroll
        for (int msk = 16; msk <= 32; msk <<= 1) {
            float mo  = __shfl_xor(mm, msk);
            float lo_ = __shfl_xor(ll, msk);
            float mn  = fmaxf(mm, mo);
            ll = ll * __expf(mm - mn) + lo_ * __expf(mo - mn);
            mm = mn;
        }
        if (kg == 0) part[(size_t)(iw + 16 + col) * JS + js] = make_float2(mm, ll);
    }
}

// ---------------- final: merge partials, loss, reduce ----------------
__global__ void k_final(const float2* __restrict__ part, const float* __restrict__ pos,
                        float* __restrict__ out) {
    int tid = threadIdx.x;
    int i = blockIdx.x * 256 + tid;
    const float2* p = part + (size_t)i * JS;
    float2 v[JS];
    float M = -3e30f;
    #pragma unroll
    for (int s = 0; s < JS; ++s) { v[s] = p[s]; M = fmaxf(M, v[s].x); }
    float L = 0.0f;
    #pragma unroll
    for (int s = 0; s < JS; ++s) L += v[s].y * __expf(v[s].x - M);
    float loss = M + __logf(L) - pos[i & (HALF - 1)];

    #pragma unroll
    for (int k = 32; k; k >>= 1) loss += __shfl_down(loss, k);
    __shared__ float ps[4];
    int w = tid >> 6, lane = tid & 63;
    if (lane == 0) ps[w] = loss;
    __syncthreads();
    if (tid == 0) atomicAdd(out, (ps[0] + ps[1] + ps[2] + ps[3]) * (1.0f / (float)NROWS));
}

extern "C" void kernel_launch(void* const* d_in, const int* in_sizes, int n_in,
                              void* d_out, int out_size, void* d_ws, size_t ws_size,
                              hipStream_t stream) {
    const float* z1 = (const float*)d_in[0];
    const float* z2 = (const float*)d_in[1];
    float* out = (float*)d_out;

    char* ws = (char*)d_ws;
    unsigned short* zb = (unsigned short*)ws;                          // 4 MiB
    float* pos  = (float*)(ws + 4u * 1024u * 1024u);                   // 16 KiB
    float2* part = (float2*)(ws + 4u * 1024u * 1024u + 65536u);        // 2 MiB
    
    k_prep <<<1024, 256, 0, stream>>>(z1, z2, zb, pos, out);
    k_main <<<2048, 256, 0, stream>>>(zb, part);
    k_final<<<32,   256, 0, stream>>>(part, pos, out);
}

// Round 11
// 202.718 us; speedup vs baseline: 1.2670x; 1.2670x over previous
//
#include <hip/hip_runtime.h>

#define NROWS 8192
#define HALF  4096
#define DIM   256
#define JS    32                 // j-splits across grid
#define JRANGE 256               // columns per block
#define JTILES 16                // 16-row j-tiles per block
#define IPB   128                // i rows per block (4 waves x 32)
#define IPW   32                 // i rows per wave

typedef short bf16x8 __attribute__((ext_vector_type(8)));
typedef float f32x4  __attribute__((ext_vector_type(4)));

// async global->LDS, 16B per lane; LDS dest = wave-uniform base + lane*16
#define GLOAD16(g, l) __builtin_amdgcn_global_load_lds( \
    (const __attribute__((address_space(1))) unsigned int*)(g), \
    (__attribute__((address_space(3))) unsigned int*)(l), 16, 0, 0)

__device__ __forceinline__ unsigned short f2bf(float f) {
    unsigned int u = __float_as_uint(f);
    u += 0x7FFFu + ((u >> 16) & 1u);          // round-to-nearest-even
    return (unsigned short)(u >> 16);
}

// --- prep: zb = bf16(sqrt(2)*z) (MFMA then yields sim units directly),
//     exact fp32 positive dots, out = 0 ---
__global__ void k_prep(const float* __restrict__ z1, const float* __restrict__ z2,
                       unsigned short* __restrict__ zb, float* __restrict__ pos,
                       float* __restrict__ out) {
    if (blockIdx.x == 0 && threadIdx.x == 0) *out = 0.0f;
    const float R2 = 1.41421356237309515f;     // sqrt(2): (R2*z)·(R2*z) = 2*z·z = sim
    int w = threadIdx.x >> 6, lane = threadIdx.x & 63;
    int row = blockIdx.x * 4 + w;              // 0 .. 4095
    float4 a = *(const float4*)(z1 + (size_t)row * DIM + lane * 4);
    float4 b = *(const float4*)(z2 + (size_t)row * DIM + lane * 4);

    uint2 pa, pb;
    pa.x = (unsigned int)f2bf(a.x*R2) | ((unsigned int)f2bf(a.y*R2) << 16);
    pa.y = (unsigned int)f2bf(a.z*R2) | ((unsigned int)f2bf(a.w*R2) << 16);
    pb.x = (unsigned int)f2bf(b.x*R2) | ((unsigned int)f2bf(b.y*R2) << 16);
    pb.y = (unsigned int)f2bf(b.z*R2) | ((unsigned int)f2bf(b.w*R2) << 16);
    *(uint2*)(zb + (size_t)row * DIM + lane * 4)          = pa;
    *(uint2*)(zb + (size_t)(row + HALF) * DIM + lane * 4) = pb;

    float d = a.x * b.x + a.y * b.y + a.z * b.z + a.w * b.w;
    #pragma unroll
    for (int k = 32; k; k >>= 1) d += __shfl_xor(d, k);
    if (lane == 0) pos[row] = 2.0f * d;        // exact fp32, sim units
}

// ---------------- main: MFMA matmul + online LSE ----------------
// Round-10 lesson: 2x af[8] + bf over-subscribed regs -> scratch spill (WRITE
// 261MB). Round-9 fact: bf[2][8] lives in AGPRs (VGPR_Count=64, correct
// results). Rounds 6/9: MfmaUtil ~30%, no pipe saturated -> accumulator dep
// distance 2 < MFMA latency is the theory. Fix: tile-PAIR compute, af in
// k-halves: 4 independent chains (dep dist 4), live regs ~140 <= 170 @ 3/CU.
__global__ __launch_bounds__(256, 3)
void k_main(const unsigned short* __restrict__ zb, float2* __restrict__ part) {
    __shared__ __align__(16) char lds[4][8192];  // 4 static 16-row buffers
    char* ldsflat = &lds[0][0];

    const int tid  = threadIdx.x;
    const int w    = tid >> 6;
    const int lane = tid & 63;
    const int col  = lane & 15;        // i-local / j-row within tile
    const int kg   = lane >> 4;        // k-group
    const int ib   = blockIdx.x & 63;  // 64 i-tiles of 128
    const int js   = blockIdx.x >> 6;  // 32 j-splits
    const int iw   = ib * IPB + w * IPW;
    const int jb0  = js * JRANGE;
    const int swz  = (lane & 7) << 4;  // read-side XOR key ((row&7)<<4), row=col
    const int dr   = col - kg * 4;     // acc reg index hitting the diagonal

    const char* zbb = (const char*)zb;

    // pre-swizzled global source offsets (involution of the LDS XOR swizzle)
    const int jp0 = w * 1024 + lane * 16;          // chunk 0 phys
    const int jp1 = 4096 + jp0;                    // chunk 1 phys
    const int jg0 = jp0 ^ (((jp0 >> 9) & 7) << 4);
    const int jg1 = jp1 ^ (((jp1 >> 9) & 7) << 4);

    // ---- i-panel prologue: global -> LDS (async, pre-swizzled) -> registers ----
    bf16x8 bf[2][8];                   // wave's 32 i-rows (AGPR-resident)
    {
        int igo[4];
        #pragma unroll
        for (int k = 0; k < 4; ++k) {
            int p = k * 4096 + w * 1024 + lane * 16;
            igo[k] = p ^ (((p >> 9) & 7) << 4);
        }
        #pragma unroll
        for (int q = 0; q < 4; ++q) {             // pass q: rows [32q, 32q+32)
            const char* gib = zbb + (size_t)(ib * IPB + q * 32) * 512;
            #pragma unroll
            for (int k = 0; k < 4; ++k)
                GLOAD16(gib + igo[k], ldsflat + k * 4096 + w * 1024);
            __syncthreads();                      // drains vmcnt -> data in LDS
            if (q == w) {                         // wave w owns pass w
                #pragma unroll
                for (int h = 0; h < 2; ++h) {
                    const char* tb = ldsflat + h * 8192;
                    #pragma unroll
                    for (int kk = 0; kk < 8; ++kk)
                        bf[h][kk] =
                            *(const bf16x8*)(tb + col * 512 + (((kk << 6) | (kg << 4)) ^ swz));
                }
            }
            __syncthreads();
        }
    }

    float m0 = -1e30f, m1 = -1e30f, l0 = 0.0f, l1 = 0.0f;

    // static af addressing: one base + per-kk lane consts + buffer imm offsets
    const char* ap = ldsflat + col * 512;
    int aoff[8];
    #pragma unroll
    for (int kk = 0; kk < 8; ++kk) aoff[kk] = ((kk << 6) | (kg << 4)) ^ swz;

    const int dt = (iw - jb0) >> 4;                // tile idx of diagonal, subtile 0
    const char* jbase = zbb + (size_t)jb0 * 512;

#define JSTAGE(T, B) do { \
    GLOAD16(jbase + (size_t)(T) * 8192 + jg0, ldsflat + (B) * 8192 + w * 1024); \
    GLOAD16(jbase + (size_t)(T) * 8192 + jg1, ldsflat + (B) * 8192 + 4096 + w * 1024); \
} while (0)

#define MASKD(X) do { \
    _Pragma("unroll") \
    for (int r = 0; r < 4; ++r) if (dr == r) X[r] = -1e30f; \
} while (0)

#define LSE0(X) do { \
    float t0 = fmaxf(fmaxf(X[0], X[1]), fmaxf(X[2], X[3])); \
    if (__any(t0 > m0)) { \
        float mn = fmaxf(m0, t0); \
        l0 *= __expf(m0 - mn); \
        m0 = mn; \
    } \
    l0 += __expf(X[0] - m0) + __expf(X[1] - m0) \
        + __expf(X[2] - m0) + __expf(X[3] - m0); \
} while (0)

#define LSE1(X) do { \
    float t0 = fmaxf(fmaxf(X[0], X[1]), fmaxf(X[2], X[3])); \
    if (__any(t0 > m1)) { \
        float mn = fmaxf(m1, t0); \
        l1 *= __expf(m1 - mn); \
        m1 = mn; \
    } \
    l1 += __expf(X[0] - m1) + __expf(X[1] - m1) \
        + __expf(X[2] - m1) + __expf(X[3] - m1); \
} while (0)

// tile-pair compute: buffers Ba (tile Ta) and Bb (tile Tb=Ta+1).
// 4 independent MFMA chains (a0,a1,b0,b1): dep distance 4 >= MFMA latency.
// af loaded in k-halves: 32 live af VGPRs max.
#define COMP_PAIR(Ba, Bb, Ta, Tb) do { \
    f32x4 a0 = {0.f, 0.f, 0.f, 0.f}; \
    f32x4 a1 = a0, b0 = a0, b1 = a0; \
    bf16x8 afa[4], afb[4]; \
    _Pragma("unroll") \
    for (int kk = 0; kk < 4; ++kk) { \
        afa[kk] = *(const bf16x8*)(ap + aoff[kk] + (Ba) * 8192); \
        afb[kk] = *(const bf16x8*)(ap + aoff[kk] + (Bb) * 8192); \
    } \
    _Pragma("unroll") \
    for (int kk = 0; kk < 4; ++kk) { \
        a0 = __builtin_amdgcn_mfma_f32_16x16x32_bf16(afa[kk], bf[0][kk], a0, 0, 0, 0); \
        a1 = __builtin_amdgcn_mfma_f32_16x16x32_bf16(afa[kk], bf[1][kk], a1, 0, 0, 0); \
        b0 = __builtin_amdgcn_mfma_f32_16x16x32_bf16(afb[kk], bf[0][kk], b0, 0, 0, 0); \
        b1 = __builtin_amdgcn_mfma_f32_16x16x32_bf16(afb[kk], bf[1][kk], b1, 0, 0, 0); \
    } \
    _Pragma("unroll") \
    for (int kk = 0; kk < 4; ++kk) { \
        afa[kk] = *(const bf16x8*)(ap + aoff[kk + 4] + (Ba) * 8192); \
        afb[kk] = *(const bf16x8*)(ap + aoff[kk + 4] + (Bb) * 8192); \
    } \
    _Pragma("unroll") \
    for (int kk = 0; kk < 4; ++kk) { \
        a0 = __builtin_amdgcn_mfma_f32_16x16x32_bf16(afa[kk], bf[0][kk + 4], a0, 0, 0, 0); \
        a1 = __builtin_amdgcn_mfma_f32_16x16x32_bf16(afa[kk], bf[1][kk + 4], a1, 0, 0, 0); \
        b0 = __builtin_amdgcn_mfma_f32_16x16x32_bf16(afb[kk], bf[0][kk + 4], b0, 0, 0, 0); \
        b1 = __builtin_amdgcn_mfma_f32_16x16x32_bf16(afb[kk], bf[1][kk + 4], b1, 0, 0, 0); \
    } \
    const int dda = (Ta) - dt; \
    const int ddb = (Tb) - dt; \
    if (dda == 0) MASKD(a0); \
    if (dda == 1) MASKD(a1); \
    if (ddb == 0) MASKD(b0); \
    if (ddb == 1) MASKD(b1); \
    LSE0(a0); \
    LSE1(a1); \
    LSE0(b0); \
    LSE1(b1); \
} while (0)

    // prologue: tiles 0,1 -> L0,L1
    JSTAGE(0, 0); JSTAGE(1, 1);
    __syncthreads();

    for (int u = 0; u < JTILES / 4; ++u) {
        const int t = u * 4;
        // half A: stage t+2,t+3 -> L2,L3 ; compute pair (t, t+1) from L0,L1
        JSTAGE(t + 2, 2); JSTAGE(t + 3, 3);
        COMP_PAIR(0, 1, t, t + 1);
        __syncthreads();
        // half B: stage t+4,t+5 -> L0,L1 ; compute pair (t+2, t+3) from L2,L3
        if (u < JTILES / 4 - 1) { JSTAGE(t + 4, 0); JSTAGE(t + 5, 1); }
        COMP_PAIR(2, 3, t + 2, t + 3);
        __syncthreads();
    }

    // merge the 4 kg groups holding the same i
    {
        float mm = m0, ll = l0;
        #pragma unroll
        for (int msk = 16; msk <= 32; msk <<= 1) {
            float mo  = __shfl_xor(mm, msk);
            float lo_ = __shfl_xor(ll, msk);
            float mn  = fmaxf(mm, mo);
            ll = ll * __expf(mm - mn) + lo_ * __expf(mo - mn);
            mm = mn;
        }
        if (kg == 0) part[(size_t)(iw + col) * JS + js] = make_float2(mm, ll);
    }
    {
        float mm = m1, ll = l1;
        #pragma unroll
        for (int msk = 16; msk <= 32; msk <<= 1) {
            float mo  = __shfl_xor(mm, msk);
            float lo_ = __shfl_xor(ll, msk);
            float mn  = fmaxf(mm, mo);
            ll = ll * __expf(mm - mn) + lo_ * __expf(mo - mn);
            mm = mn;
        }
        if (kg == 0) part[(size_t)(iw + 16 + col) * JS + js] = make_float2(mm, ll);
    }
#undef JSTAGE
#undef MASKD
#undef LSE0
#undef LSE1
#undef COMP_PAIR
}

// ---------------- final: merge partials, loss, reduce ----------------
__global__ void k_final(const float2* __restrict__ part, const float* __restrict__ pos,
                        float* __restrict__ out) {
    int tid = threadIdx.x;
    int i = blockIdx.x * 256 + tid;
    const float2* p = part + (size_t)i * JS;
    float M = -3e30f;
    float2 v[JS];
    #pragma unroll
    for (int s = 0; s < JS; ++s) { v[s] = p[s]; M = fmaxf(M, v[s].x); }
    float L = 0.0f;
    #pragma unroll
    for (int s = 0; s < JS; ++s) L += v[s].y * __expf(v[s].x - M);
    float loss = M + __logf(L) - pos[i & (HALF - 1)];

    #pragma unroll
    for (int k = 32; k; k >>= 1) loss += __shfl_down(loss, k);
    __shared__ float ps[4];
    int w = tid >> 6, lane = tid & 63;
    if (lane == 0) ps[w] = loss;
    __syncthreads();
    if (tid == 0) atomicAdd(out, (ps[0] + ps[1] + ps[2] + ps[3]) * (1.0f / (float)NROWS));
}

extern "C" void kernel_launch(void* const* d_in, const int* in_sizes, int n_in,
                              void* d_out, int out_size, void* d_ws, size_t ws_size,
                              hipStream_t stream) {
    const float* z1 = (const float*)d_in[0];
    const float* z2 = (const float*)d_in[1];
    float* out = (float*)d_out;

    char* ws = (char*)d_ws;
    unsigned short* zb = (unsigned short*)ws;                          // 4 MiB
    float* pos  = (float*)(ws + 4u * 1024u * 1024u);                   // 16 KiB
    float2* part = (float2*)(ws + 4u * 1024u * 1024u + 65536u);        // 2 MiB

    k_prep <<<1024, 256, 0, stream>>>(z1, z2, zb, pos, out);
    k_main <<<2048, 256, 0, stream>>>(zb, part);
    k_final<<<32,   256, 0, stream>>>(part, pos, out);
}

// Round 12
// 130.094 us; speedup vs baseline: 1.9742x; 1.5582x over previous
//
#include <hip/hip_runtime.h>

#define NROWS 8192
#define HALF  4096
#define DIM   256
#define JS    16                 // j-splits across grid
#define JRANGE 512               // columns per block
#define JTILES 32                // 16-row j-tiles per block
#define IPB   128                // i rows per block (4 waves x 32)
#define IPW   32                 // i rows per wave

typedef short bf16x8 __attribute__((ext_vector_type(8)));
typedef float f32x4  __attribute__((ext_vector_type(4)));

// async global->LDS, 16B per lane; LDS dest = wave-uniform base + lane*16
#define GLOAD16(g, l) __builtin_amdgcn_global_load_lds( \
    (const __attribute__((address_space(1))) unsigned int*)(g), \
    (__attribute__((address_space(3))) unsigned int*)(l), 16, 0, 0)

__device__ __forceinline__ unsigned short f2bf(float f) {
    unsigned int u = __float_as_uint(f);
    u += 0x7FFFu + ((u >> 16) & 1u);          // round-to-nearest-even
    return (unsigned short)(u >> 16);
}

// --- prep: zb = bf16(sqrt(2)*z) (MFMA then yields sim units directly),
//     exact fp32 positive dots, out = 0 ---
__global__ void k_prep(const float* __restrict__ z1, const float* __restrict__ z2,
                       unsigned short* __restrict__ zb, float* __restrict__ pos,
                       float* __restrict__ out) {
    if (blockIdx.x == 0 && threadIdx.x == 0) *out = 0.0f;
    const float R2 = 1.41421356237309515f;     // sqrt(2): (R2*z)·(R2*z) = 2*z·z = sim
    int w = threadIdx.x >> 6, lane = threadIdx.x & 63;
    int row = blockIdx.x * 4 + w;              // 0 .. 4095
    float4 a = *(const float4*)(z1 + (size_t)row * DIM + lane * 4);
    float4 b = *(const float4*)(z2 + (size_t)row * DIM + lane * 4);

    uint2 pa, pb;
    pa.x = (unsigned int)f2bf(a.x*R2) | ((unsigned int)f2bf(a.y*R2) << 16);
    pa.y = (unsigned int)f2bf(a.z*R2) | ((unsigned int)f2bf(a.w*R2) << 16);
    pb.x = (unsigned int)f2bf(b.x*R2) | ((unsigned int)f2bf(b.y*R2) << 16);
    pb.y = (unsigned int)f2bf(b.z*R2) | ((unsigned int)f2bf(b.w*R2) << 16);
    *(uint2*)(zb + (size_t)row * DIM + lane * 4)          = pa;
    *(uint2*)(zb + (size_t)(row + HALF) * DIM + lane * 4) = pb;

    float d = a.x * b.x + a.y * b.y + a.z * b.z + a.w * b.w;
    #pragma unroll
    for (int k = 32; k; k >>= 1) d += __shfl_xor(d, k);
    if (lane == 0) pos[row] = 2.0f * d;        // exact fp32, sim units
}

// ---------------- main: MFMA matmul + online LSE ----------------
// Round-11 post-mortem: the 145us regression was L2 THRASH (FETCH 194MB) from
// grid 2048, not spill (WRITE ~256MB rows = harness d_ws poison in counter
// window). Round-9 geometry (grid 1024, JS=16, FETCH 18.8MB) is L2-clean.
// This round: identical geometry, ONLY the inner loop changes to 4 independent
// MFMA chains (tile-pair, af in k-pairs) -> dep distance 4 >= MFMA latency.
// Register law (m69): 128 total/wave for 4 waves/SIMD. Steady state here:
// afa[2]+afb[2]=16 + acc 16 + misc ~32 = 64 arch + bf[2][8]=64 AGPR = 128.
__global__ __launch_bounds__(256, 4)
void k_main(const unsigned short* __restrict__ zb, float2* __restrict__ part) {
    __shared__ __align__(16) char lds[4][8192];  // 4 static 16-row buffers
    char* ldsflat = &lds[0][0];

    const int tid  = threadIdx.x;
    const int w    = tid >> 6;
    const int lane = tid & 63;
    const int col  = lane & 15;        // i-local / j-row within tile
    const int kg   = lane >> 4;        // k-group
    const int ib   = blockIdx.x & 63;  // 64 i-tiles of 128
    const int js   = blockIdx.x >> 6;  // 16 j-splits
    const int iw   = ib * IPB + w * IPW;
    const int jb0  = js * JRANGE;
    const int swz  = (lane & 7) << 4;  // read-side XOR key ((row&7)<<4), row=col
    const int dr   = col - kg * 4;     // acc reg index hitting the diagonal

    const char* zbb = (const char*)zb;

    // pre-swizzled global source offsets (involution of the LDS XOR swizzle)
    const int jp0 = w * 1024 + lane * 16;          // chunk 0 phys
    const int jp1 = 4096 + jp0;                    // chunk 1 phys
    const int jg0 = jp0 ^ (((jp0 >> 9) & 7) << 4);
    const int jg1 = jp1 ^ (((jp1 >> 9) & 7) << 4);

    // ---- i-panel prologue: global -> LDS (async, pre-swizzled) -> registers ----
    bf16x8 bf[2][8];                   // wave's 32 i-rows (AGPR-resident)
    {
        int igo[4];
        #pragma unroll
        for (int k = 0; k < 4; ++k) {
            int p = k * 4096 + w * 1024 + lane * 16;
            igo[k] = p ^ (((p >> 9) & 7) << 4);
        }
        #pragma unroll
        for (int q = 0; q < 4; ++q) {             // pass q: rows [32q, 32q+32)
            const char* gib = zbb + (size_t)(ib * IPB + q * 32) * 512;
            #pragma unroll
            for (int k = 0; k < 4; ++k)
                GLOAD16(gib + igo[k], ldsflat + k * 4096 + w * 1024);
            __syncthreads();                      // drains vmcnt -> data in LDS
            if (q == w) {                         // wave w owns pass w
                #pragma unroll
                for (int h = 0; h < 2; ++h) {
                    const char* tb = ldsflat + h * 8192;
                    #pragma unroll
                    for (int kk = 0; kk < 8; ++kk)
                        bf[h][kk] =
                            *(const bf16x8*)(tb + col * 512 + (((kk << 6) | (kg << 4)) ^ swz));
                }
            }
            __syncthreads();
        }
    }

    float m0 = -1e30f, m1 = -1e30f, l0 = 0.0f, l1 = 0.0f;

    // static af addressing: one base + per-kk lane consts + buffer imm offsets
    const char* ap = ldsflat + col * 512;
    int aoff[8];
    #pragma unroll
    for (int kk = 0; kk < 8; ++kk) aoff[kk] = ((kk << 6) | (kg << 4)) ^ swz;

    const int dt = (iw - jb0) >> 4;                // tile idx of diagonal, subtile 0
    const char* jbase = zbb + (size_t)jb0 * 512;

#define JSTAGE(T, B) do { \
    GLOAD16(jbase + (size_t)(T) * 8192 + jg0, ldsflat + (B) * 8192 + w * 1024); \
    GLOAD16(jbase + (size_t)(T) * 8192 + jg1, ldsflat + (B) * 8192 + 4096 + w * 1024); \
} while (0)

#define MASKD(X) do { \
    _Pragma("unroll") \
    for (int r = 0; r < 4; ++r) if (dr == r) X[r] = -1e30f; \
} while (0)

#define LSE0(X) do { \
    float t0 = fmaxf(fmaxf(X[0], X[1]), fmaxf(X[2], X[3])); \
    if (__any(t0 > m0)) { \
        float mn = fmaxf(m0, t0); \
        l0 *= __expf(m0 - mn); \
        m0 = mn; \
    } \
    l0 += __expf(X[0] - m0) + __expf(X[1] - m0) \
        + __expf(X[2] - m0) + __expf(X[3] - m0); \
} while (0)

#define LSE1(X) do { \
    float t0 = fmaxf(fmaxf(X[0], X[1]), fmaxf(X[2], X[3])); \
    if (__any(t0 > m1)) { \
        float mn = fmaxf(m1, t0); \
        l1 *= __expf(m1 - mn); \
        m1 = mn; \
    } \
    l1 += __expf(X[0] - m1) + __expf(X[1] - m1) \
        + __expf(X[2] - m1) + __expf(X[3] - m1); \
} while (0)

// tile-pair compute, af loaded in k-PAIRS (16 VGPR live): 4 independent MFMA
// chains (a0,a1,b0,b1) -> dep distance 4 (~19.4 cyc) >= MFMA latency.
#define COMP_PAIR(Ba, Bb, Ta, Tb) do { \
    f32x4 a0 = {0.f, 0.f, 0.f, 0.f}; \
    f32x4 a1 = a0, b0 = a0, b1 = a0; \
    _Pragma("unroll") \
    for (int g = 0; g < 4; ++g) { \
        bf16x8 afa0 = *(const bf16x8*)(ap + aoff[2 * g]     + (Ba) * 8192); \
        bf16x8 afa1 = *(const bf16x8*)(ap + aoff[2 * g + 1] + (Ba) * 8192); \
        bf16x8 afb0 = *(const bf16x8*)(ap + aoff[2 * g]     + (Bb) * 8192); \
        bf16x8 afb1 = *(const bf16x8*)(ap + aoff[2 * g + 1] + (Bb) * 8192); \
        a0 = __builtin_amdgcn_mfma_f32_16x16x32_bf16(afa0, bf[0][2 * g],     a0, 0, 0, 0); \
        a1 = __builtin_amdgcn_mfma_f32_16x16x32_bf16(afa0, bf[1][2 * g],     a1, 0, 0, 0); \
        b0 = __builtin_amdgcn_mfma_f32_16x16x32_bf16(afb0, bf[0][2 * g],     b0, 0, 0, 0); \
        b1 = __builtin_amdgcn_mfma_f32_16x16x32_bf16(afb0, bf[1][2 * g],     b1, 0, 0, 0); \
        a0 = __builtin_amdgcn_mfma_f32_16x16x32_bf16(afa1, bf[0][2 * g + 1], a0, 0, 0, 0); \
        a1 = __builtin_amdgcn_mfma_f32_16x16x32_bf16(afa1, bf[1][2 * g + 1], a1, 0, 0, 0); \
        b0 = __builtin_amdgcn_mfma_f32_16x16x32_bf16(afb1, bf[0][2 * g + 1], b0, 0, 0, 0); \
        b1 = __builtin_amdgcn_mfma_f32_16x16x32_bf16(afb1, bf[1][2 * g + 1], b1, 0, 0, 0); \
    } \
    const int dda = (Ta) - dt; \
    const int ddb = (Tb) - dt; \
    if (dda == 0) MASKD(a0); \
    if (dda == 1) MASKD(a1); \
    if (ddb == 0) MASKD(b0); \
    if (ddb == 1) MASKD(b1); \
    LSE0(a0); \
    LSE1(a1); \
    LSE0(b0); \
    LSE1(b1); \
} while (0)

    // prologue: tiles 0,1 -> L0,L1
    JSTAGE(0, 0); JSTAGE(1, 1);
    __syncthreads();

    for (int u = 0; u < JTILES / 4; ++u) {
        const int t = u * 4;
        // half A: stage t+2,t+3 -> L2,L3 ; compute pair (t, t+1) from L0,L1
        JSTAGE(t + 2, 2); JSTAGE(t + 3, 3);
        COMP_PAIR(0, 1, t, t + 1);
        __syncthreads();
        // half B: stage t+4,t+5 -> L0,L1 ; compute pair (t+2, t+3) from L2,L3
        if (u < JTILES / 4 - 1) { JSTAGE(t + 4, 0); JSTAGE(t + 5, 1); }
        COMP_PAIR(2, 3, t + 2, t + 3);
        __syncthreads();
    }

    // merge the 4 kg groups holding the same i
    {
        float mm = m0, ll = l0;
        #pragma unroll
        for (int msk = 16; msk <= 32; msk <<= 1) {
            float mo  = __shfl_xor(mm, msk);
            float lo_ = __shfl_xor(ll, msk);
            float mn  = fmaxf(mm, mo);
            ll = ll * __expf(mm - mn) + lo_ * __expf(mo - mn);
            mm = mn;
        }
        if (kg == 0) part[(size_t)(iw + col) * JS + js] = make_float2(mm, ll);
    }
    {
        float mm = m1, ll = l1;
        #pragma unroll
        for (int msk = 16; msk <= 32; msk <<= 1) {
            float mo  = __shfl_xor(mm, msk);
            float lo_ = __shfl_xor(ll, msk);
            float mn  = fmaxf(mm, mo);
            ll = ll * __expf(mm - mn) + lo_ * __expf(mo - mn);
            mm = mn;
        }
        if (kg == 0) part[(size_t)(iw + 16 + col) * JS + js] = make_float2(mm, ll);
    }
#undef JSTAGE
#undef MASKD
#undef LSE0
#undef LSE1
#undef COMP_PAIR
}

// ---------------- final: merge partials, loss, reduce ----------------
__global__ void k_final(const float2* __restrict__ part, const float* __restrict__ pos,
                        float* __restrict__ out) {
    int tid = threadIdx.x;
    int i = blockIdx.x * 256 + tid;
    const float2* p = part + (size_t)i * JS;
    float2 v[JS];
    float M = -3e30f;
    #pragma unroll
    for (int s = 0; s < JS; ++s) { v[s] = p[s]; M = fmaxf(M, v[s].x); }
    float L = 0.0f;
    #pragma unroll
    for (int s = 0; s < JS; ++s) L += v[s].y * __expf(v[s].x - M);
    float loss = M + __logf(L) - pos[i & (HALF - 1)];

    #pragma unroll
    for (int k = 32; k; k >>= 1) loss += __shfl_down(loss, k);
    __shared__ float ps[4];
    int w = tid >> 6, lane = tid & 63;
    if (lane == 0) ps[w] = loss;
    __syncthreads();
    if (tid == 0) atomicAdd(out, (ps[0] + ps[1] + ps[2] + ps[3]) * (1.0f / (float)NROWS));
}

extern "C" void kernel_launch(void* const* d_in, const int* in_sizes, int n_in,
                              void* d_out, int out_size, void* d_ws, size_t ws_size,
                              hipStream_t stream) {
    const float* z1 = (const float*)d_in[0];
    const float* z2 = (const float*)d_in[1];
    float* out = (float*)d_out;

    char* ws = (char*)d_ws;
    unsigned short* zb = (unsigned short*)ws;                          // 4 MiB
    float* pos  = (float*)(ws + 4u * 1024u * 1024u);                   // 16 KiB
    float2* part = (float2*)(ws + 4u * 1024u * 1024u + 65536u);        // 1 MiB

    k_prep <<<1024, 256, 0, stream>>>(z1, z2, zb, pos, out);
    k_main <<<1024, 256, 0, stream>>>(zb, part);
    k_final<<<32,   256, 0, stream>>>(part, pos, out);
}